// Round 9
// baseline (131.914 us; speedup 1.0000x reference)
//
#include <hip/hip_runtime.h>

// Part_CAM: only parts e=1..4 survive feat_cam[:,1:].
// Row-0-of-chain: e0^T * (sub[11] @ ... @ sub[0]) as 12 vec-mat products.
// Round 9: r8's fused all-parts-per-b design with two robustness fixes:
//  (1) LEAD=6 / RING=8 -> glds re-writes a slot consumed 2 iterations ago
//      (r8 re-wrote the slot consumed on the PREVIOUS iteration: WAR margin 1).
//  (2) deterministic 4-pass tree reduction (ds_write + fixed-order sum)
//      replaces LDS atomicAdd (non-deterministic order).

#define L_ 12
#define B_ 64
#define N_ 201
#define D_ 768
#define NN_ ((size_t)N_ * N_)

#define RING 8
#define LEAD 6
#define RP 13            // rows per wave per layer (16 waves x 13 >= 201)

// barrier that drains LDS ops but NOT vmcnt (prefetch survives)
#define BAR() asm volatile("s_waitcnt lgkmcnt(0)\n\ts_barrier" ::: "memory")
#define WAITC(n) asm volatile("s_waitcnt vmcnt(" #n ")" ::: "memory")

__device__ __forceinline__ void glds4(const float* g, float* l) {
    __builtin_amdgcn_global_load_lds(
        (const __attribute__((address_space(1))) void*)g,
        (__attribute__((address_space(3))) void*)l, 4, 0, 0);
}

__device__ __forceinline__ bool in_part(int p, int g) {
    const int e = p + 1;
    const int s = (p == 0) ? 5 : (p == 1) ? 5 : (p == 2) ? 54 : 103;
    const int t = (p == 0) ? 201 : (p == 1) ? 103 : (p == 2) ? 152 : 201;
    return (g == e) || (g >= s && g < t);
}

__global__ __launch_bounds__(1024) void part_cam_chain(
    const float* __restrict__ x,     // (L, B, N, N)
    float* __restrict__ wbuf)        // ws: (4, B, 256)
{
    __shared__ __align__(16) float ring[16 * RING * 256];  // 128 KB
    __shared__ __align__(16) float vAll[256 * 4];          // [g][p], 4 KB
    __shared__ __align__(16) float red[16 * 256];          // 16 KB

    const int b    = blockIdx.x;
    const int tid  = threadIdx.x;
    const int lane = tid & 63;
    const int w    = tid >> 6;       // wave 0..15 (row group)

    int cadd[4];
    #pragma unroll
    for (int i = 0; i < 4; ++i) {
        int col = i * 64 + lane;
        cadd[i] = (col <= 200) ? col : 200;
    }

    auto ISSUE = [&](const float* xl, int j, int isl) {
        int rr = 1 + w * RP + j;
        if (rr > 200) rr = 0;        // row 0 has v==0 for all parts (harmless)
        const float* rowp = xl + (size_t)rr * N_;
        float* sb = ring + (((size_t)w * RING + isl) << 8);
        #pragma unroll
        for (int i = 0; i < 4; ++i)
            glds4(rowp + cadd[i], sb + i * 64);
    };

    // init loads (oldest in vmcnt queue), then prologue issues
    float iv0 = 0.f, iv1 = 0.f, iv2 = 0.f, iv3 = 0.f;
    if (tid < 256) {
        const float* x11 = x + ((size_t)11 * B_ + b) * NN_;
        const int g = (tid <= 200) ? tid : 200;
        iv0 = x11[(size_t)1 * N_ + g];
        iv1 = x11[(size_t)2 * N_ + g];
        iv2 = x11[(size_t)3 * N_ + g];
        iv3 = x11[(size_t)4 * N_ + g];
    }

    const float* xli = x + ((size_t)10 * B_ + b) * NN_;
    #pragma unroll
    for (int g0 = 0; g0 < LEAD; ++g0) ISSUE(xli, g0, g0);
    int ji = LEAD, sl = 0;

    if (tid < 256) {
        vAll[tid * 4 + 0] = in_part(0, tid) ? iv0 : 0.f;
        vAll[tid * 4 + 1] = in_part(1, tid) ? iv1 : 0.f;
        vAll[tid * 4 + 2] = in_part(2, tid) ? iv2 : 0.f;
        vAll[tid * 4 + 3] = in_part(3, tid) ? iv3 : 0.f;
    }
    BAR();

    float4 acc0 = {0,0,0,0}, acc1 = {0,0,0,0}, acc2 = {0,0,0,0}, acc3 = {0,0,0,0};

    auto CONSUME = [&](int j) {
        const float* sb = ring + (((size_t)w * RING + sl) << 8);
        float4 xv = *(const float4*)(sb + lane * 4);
        int rr = 1 + w * RP + j;
        if (rr > 200) rr = 0;
        float4 vv = *(const float4*)(vAll + rr * 4);   // broadcast: 4 parts' v[rr]
        acc0.x += vv.x * xv.x; acc0.y += vv.x * xv.y; acc0.z += vv.x * xv.z; acc0.w += vv.x * xv.w;
        acc1.x += vv.y * xv.x; acc1.y += vv.y * xv.y; acc1.z += vv.y * xv.z; acc1.w += vv.y * xv.w;
        acc2.x += vv.z * xv.x; acc2.y += vv.z * xv.y; acc2.z += vv.z * xv.z; acc2.w += vv.z * xv.w;
        acc3.x += vv.w * xv.x; acc3.y += vv.w * xv.y; acc3.z += vv.w * xv.z; acc3.w += vv.w * xv.w;
    };

    auto REDUCE = [&]() {
        #pragma unroll
        for (int pp = 0; pp < 4; ++pp) {
            float4 a = (pp == 0) ? acc0 : (pp == 1) ? acc1 : (pp == 2) ? acc2 : acc3;
            *(float4*)&red[(w << 8) + (lane << 2)] = a;   // slot q=lane*4+i == col q
            BAR();
            if (tid < 256) {
                float sum = 0.f;
                #pragma unroll
                for (int ww = 0; ww < 16; ++ww) sum += red[(ww << 8) + tid];
                vAll[tid * 4 + pp] = in_part(pp, tid) ? sum : 0.f;
            }
            BAR();
        }
        acc0 = make_float4(0,0,0,0); acc1 = make_float4(0,0,0,0);
        acc2 = make_float4(0,0,0,0); acc3 = make_float4(0,0,0,0);
    };

    for (int l = 10; l >= 1; --l) {
        #pragma unroll
        for (int j = 0; j < RP; ++j) {
            WAITC(20);               // 6 slots in flight; oldest landed
            CONSUME(j);
            int isl = sl + LEAD; if (isl >= RING) isl -= RING;
            ISSUE(xli, ji, isl);     // writes slot consumed 2 iterations ago
            ji++;
            if (ji == RP) { ji = 0; xli -= (size_t)B_ * NN_; }
            sl = (sl + 1 == RING) ? 0 : sl + 1;
        }
        REDUCE();
    }
    #pragma unroll
    for (int j = 0; j < RP; ++j) {
        if (j < RP - LEAD) { WAITC(20); }
        else if (j == RP - LEAD) { WAITC(0); }
        CONSUME(j);
        if (j < RP - LEAD) {
            int isl = sl + LEAD; if (isl >= RING) isl -= RING;
            ISSUE(xli, ji, isl);
            ji++;
        }
        sl = (sl + 1 == RING) ? 0 : sl + 1;
    }
    REDUCE();

    {
        int p = tid >> 8, k = tid & 255;
        const int sp = (p == 0) ? 5 : (p == 1) ? 5 : (p == 2) ? 54 : 103;
        const int Kp = (p == 0) ? 196 : 98;
        float val = (k < Kp) ? vAll[(sp + k) * 4 + p] : 0.f;
        wbuf[((size_t)p * B_ + b) * 256 + k] = val;
    }
}

__global__ __launch_bounds__(256) void part_cam_epi(
    const float* __restrict__ feat,  // (B, N, D)
    const float* __restrict__ wbuf,  // (4, B, 256)
    float* __restrict__ out)         // (B, 4, D)
{
    const int bid = blockIdx.x;      // 64*12
    const int b   = bid / 12;
    const int rem = bid % 12;
    const int p   = rem / 3;
    const int dc  = rem % 3;
    const int s = (p == 0) ? 5 : (p == 1) ? 5 : (p == 2) ? 54 : 103;
    const int K = (p == 0) ? 196 : 98;
    const int tid = threadIdx.x;

    __shared__ float wsh[256];
    wsh[tid] = wbuf[((size_t)p * B_ + b) * 256 + tid];
    __syncthreads();

    const int d = dc * 256 + tid;
    const float* fb = feat + (size_t)b * N_ * D_ + d;
    float acc = 0.f;
    for (int k = 0; k < K; k += 16) {
        float f[16];
        #pragma unroll
        for (int jj = 0; jj < 16; ++jj)
            if (k + jj < K) f[jj] = fb[(size_t)(s + k + jj) * D_];
        #pragma unroll
        for (int jj = 0; jj < 16; ++jj)
            if (k + jj < K) acc += wsh[k + jj] * fmaxf(f[jj], 0.f);
    }
    out[((size_t)b * 4 + p) * D_ + d] = acc;
}

extern "C" void kernel_launch(void* const* d_in, const int* in_sizes, int n_in,
                              void* d_out, int out_size, void* d_ws, size_t ws_size,
                              hipStream_t stream) {
    const float* x    = (const float*)d_in[0];
    const float* feat = (const float*)d_in[1];
    float* out = (float*)d_out;
    float* w   = (float*)d_ws;       // 4*64*256 floats = 256 KiB
    part_cam_chain<<<dim3(64), dim3(1024), 0, stream>>>(x, w);
    part_cam_epi<<<dim3(768), dim3(256), 0, stream>>>(feat, w, out);
}